// Round 1
// baseline (159.284 us; speedup 1.0000x reference)
//
#include <hip/hip_runtime.h>

#define NROWS   16384
#define NCOL    4096
#define NSTAGES 12
#define NPAIRS  2048
#define RPB     4   // rows per block

// ---- LDS bank swizzles (bijective: XOR bits [4:2] with higher untouched bits) ----
// Exchange 1 layout: W1(n) = hi*256 + lo*16 + mid   (n = hi<<8 | mid<<4 | lo)
__device__ __forceinline__ int swz1(int W) {
  return W ^ (((W >> 8) & 1) << 4) ^ (((W >> 5) & 3) << 2);
}
// Exchange 2 layout: W2(n) = mid*256 + lo*16 + hi
__device__ __forceinline__ int swz2(int W) {
  return W ^ (((W >> 7) & 1) << 4) ^ (((W >> 5) & 3) << 2);
}

__global__ void cs_table_kernel(const float* __restrict__ ang, float2* __restrict__ tab) {
  int i = blockIdx.x * blockDim.x + threadIdx.x;
  if (i < NSTAGES * NPAIRS) {
    float s, c;
    sincosf(ang[i], &s, &c);
    tab[i] = make_float2(c, s);
  }
}

template <bool TAB>
__device__ __forceinline__ float2 get_cs(const float2* __restrict__ tab,
                                         const float* __restrict__ ang, int idx) {
  if constexpr (TAB) {
    return tab[idx];
  } else {
    float s, c;
    sincosf(ang[idx], &s, &c);
    return make_float2(c, s);
  }
}

template <bool TAB>
__global__ __launch_bounds__(256, 4) void butterfly_kernel(
    const float* __restrict__ x, const float2* __restrict__ tab,
    const float* __restrict__ ang, float* __restrict__ out) {
  __shared__ __align__(16) float lds[NCOL];

  const int t   = threadIdx.x;
  const int thi = t >> 4;
  const int tlo = t & 15;
  const size_t row0 = (size_t)blockIdx.x * RPB;

  float v[RPB][16];

  // ---- load, phase-1 layout: v[r][j] = x[row, t*16 + j] (bits 0-3 local) ----
#pragma unroll
  for (int r = 0; r < RPB; ++r) {
    const float4* p4 = reinterpret_cast<const float4*>(x + (row0 + r) * NCOL + t * 16);
#pragma unroll
    for (int k = 0; k < 4; ++k) {
      float4 q = p4[k];
      v[r][4 * k + 0] = q.x; v[r][4 * k + 1] = q.y;
      v[r][4 * k + 2] = q.z; v[r][4 * k + 3] = q.w;
    }
  }

  // ---- phase 1: stages 0..3 (pair dist 1,2,4,8 within the 16 local elems) ----
#pragma unroll
  for (int s = 0; s < 4; ++s) {
    float2 A[8];
#pragma unroll
    for (int p = 0; p < 8; ++p)
      A[p] = get_cs<TAB>(tab, ang, s * NPAIRS + t * 8 + p);
#pragma unroll
    for (int r = 0; r < RPB; ++r) {
#pragma unroll
      for (int p = 0; p < 8; ++p) {
        const int d  = 1 << s;
        const int j0 = ((p >> s) << (s + 1)) | (p & (d - 1));
        const int j1 = j0 + d;
        float v0 = v[r][j0], v1 = v[r][j1];
        v[r][j0] = A[p].x * v0 - A[p].y * v1;
        v[r][j1] = A[p].y * v0 + A[p].x * v1;
      }
    }
  }

  // ---- exchange 1: to phase-2 layout  v[r][i] = elem (thi*256 + i*16 + tlo) ----
#pragma unroll
  for (int r = 0; r < RPB; ++r) {
#pragma unroll
    for (int j = 0; j < 16; ++j)
      lds[swz1(thi * 256 + j * 16 + tlo)] = v[r][j];
    __syncthreads();
#pragma unroll
    for (int k = 0; k < 4; ++k) {
      float4 q = *reinterpret_cast<const float4*>(&lds[swz1(thi * 256 + tlo * 16 + 4 * k)]);
      v[r][4 * k + 0] = q.x; v[r][4 * k + 1] = q.y;
      v[r][4 * k + 2] = q.z; v[r][4 * k + 3] = q.w;
    }
    __syncthreads();
  }

  // ---- phase 2: stages 4..7 (bits 4-7 local) ----
#pragma unroll
  for (int s = 4; s < 8; ++s) {
    const int qq = s - 4;
    float2 A[8];
#pragma unroll
    for (int p = 0; p < 8; ++p)
      A[p] = get_cs<TAB>(tab, ang, s * NPAIRS + thi * 128 + p * 16 + tlo);
#pragma unroll
    for (int r = 0; r < RPB; ++r) {
#pragma unroll
      for (int p = 0; p < 8; ++p) {
        const int d  = 1 << qq;
        const int j0 = ((p >> qq) << (qq + 1)) | (p & (d - 1));
        const int j1 = j0 + d;
        float v0 = v[r][j0], v1 = v[r][j1];
        v[r][j0] = A[p].x * v0 - A[p].y * v1;
        v[r][j1] = A[p].y * v0 + A[p].x * v1;
      }
    }
  }

  // ---- exchange 2: to phase-3 layout  v[r][i] = elem (i*256 + t) ----
#pragma unroll
  for (int r = 0; r < RPB; ++r) {
#pragma unroll
    for (int j = 0; j < 16; ++j)
      lds[swz2(j * 256 + tlo * 16 + thi)] = v[r][j];
    __syncthreads();
#pragma unroll
    for (int k = 0; k < 4; ++k) {
      float4 q = *reinterpret_cast<const float4*>(&lds[swz2(thi * 256 + tlo * 16 + 4 * k)]);
      v[r][4 * k + 0] = q.x; v[r][4 * k + 1] = q.y;
      v[r][4 * k + 2] = q.z; v[r][4 * k + 3] = q.w;
    }
    __syncthreads();
  }

  // ---- phase 3: stages 8..11 (bits 8-11 local) ----
#pragma unroll
  for (int s = 8; s < 12; ++s) {
    const int qq = s - 8;
    float2 A[8];
#pragma unroll
    for (int p = 0; p < 8; ++p)
      A[p] = get_cs<TAB>(tab, ang, s * NPAIRS + p * 256 + t);
#pragma unroll
    for (int r = 0; r < RPB; ++r) {
#pragma unroll
      for (int p = 0; p < 8; ++p) {
        const int d  = 1 << qq;
        const int j0 = ((p >> qq) << (qq + 1)) | (p & (d - 1));
        const int j1 = j0 + d;
        float v0 = v[r][j0], v1 = v[r][j1];
        v[r][j0] = A[p].x * v0 - A[p].y * v1;
        v[r][j1] = A[p].y * v0 + A[p].x * v1;
      }
    }
  }

  // ---- store (phase-3 layout: elem i*256 + t -> lanes contiguous, coalesced) ----
#pragma unroll
  for (int r = 0; r < RPB; ++r) {
    float* orow = out + (row0 + r) * NCOL;
#pragma unroll
    for (int i = 0; i < 16; ++i)
      orow[i * 256 + t] = v[r][i];
  }
}

extern "C" void kernel_launch(void* const* d_in, const int* in_sizes, int n_in,
                              void* d_out, int out_size, void* d_ws, size_t ws_size,
                              hipStream_t stream) {
  const float* x   = (const float*)d_in[0];
  const float* ang = (const float*)d_in[1];
  float* out       = (float*)d_out;

  const size_t tab_bytes = (size_t)NSTAGES * NPAIRS * sizeof(float2);
  const int nblocks = NROWS / RPB;

  if (ws_size >= tab_bytes) {
    float2* tab = (float2*)d_ws;
    cs_table_kernel<<<(NSTAGES * NPAIRS + 255) / 256, 256, 0, stream>>>(ang, tab);
    butterfly_kernel<true><<<nblocks, 256, 0, stream>>>(x, tab, nullptr, out);
  } else {
    butterfly_kernel<false><<<nblocks, 256, 0, stream>>>(x, nullptr, ang, out);
  }
}

// Round 3
// 135.118 us; speedup vs baseline: 1.1789x; 1.1789x over previous
//
#include <hip/hip_runtime.h>

#define NROWS   16384
#define NCOL    4096
#define NSTAGES 12
#define NPAIRS  2048
#define RPB     2   // rows per block

// ---- LDS bank swizzles for the two exchanges (validated R1+R2) ----
__device__ __forceinline__ int swz1(int W) {
  return W ^ (((W >> 8) & 1) << 4) ^ (((W >> 5) & 3) << 2);
}
__device__ __forceinline__ int swz2(int W) {
  return W ^ (((W >> 7) & 1) << 4) ^ (((W >> 5) & 3) << 2);
}

// pair index needed by lane t, stage s, sub-pair p (matches butterfly layouts)
__device__ __forceinline__ int pair_idx(int s, int t, int p) {
  int thi = t >> 4, tlo = t & 15;
  return (s < 4) ? (t * 8 + p) : (s < 8) ? (thi * 128 + p * 16 + tlo) : (p * 256 + t);
}

// Permuted table: tab4[(s*4+k)*256 + t] = {cos,sin,cos,sin} for p=2k,2k+1.
// Makes every angle load in the butterfly a unit-stride dwordx4.
__global__ void cs_table_kernel(const float* __restrict__ ang, float4* __restrict__ tab4) {
  int tid = blockIdx.x * blockDim.x + threadIdx.x;
  if (tid >= NSTAGES * 4 * 256) return;
  int s = tid >> 10;
  int rem = tid & 1023;
  int k = rem >> 8;
  int t = rem & 255;
  float c[2], sn[2];
#pragma unroll
  for (int e = 0; e < 2; ++e) {
    int pr = pair_idx(s, t, 2 * k + e);
    float sv, cv;
    sincosf(ang[s * NPAIRS + pr], &sv, &cv);
    c[e] = cv; sn[e] = sv;
  }
  tab4[(s * 4 + k) * 256 + t] = make_float4(c[0], sn[0], c[1], sn[1]);
}

template <bool TAB>
__device__ __forceinline__ void load_A(int s, int t, const float4* __restrict__ tab4,
                                       const float* __restrict__ ang, float2* A) {
  if constexpr (TAB) {
#pragma unroll
    for (int k = 0; k < 4; ++k) {
      float4 q = tab4[(s * 4 + k) * 256 + t];
      A[2 * k]     = make_float2(q.x, q.y);
      A[2 * k + 1] = make_float2(q.z, q.w);
    }
  } else {
#pragma unroll
    for (int p = 0; p < 8; ++p) {
      float sv, cv;
      sincosf(ang[s * NPAIRS + pair_idx(s, t, p)], &sv, &cv);
      A[p] = make_float2(cv, sv);
    }
  }
}

template <bool TAB>
__global__ __launch_bounds__(256, 4) void butterfly_kernel(
    const float* __restrict__ x, const float4* __restrict__ tab4,
    const float* __restrict__ ang, float* __restrict__ out) {
  __shared__ __align__(16) float lds[RPB][NCOL];

  const int t   = threadIdx.x;
  const int thi = t >> 4;
  const int tlo = t & 15;
  const size_t row0 = (size_t)blockIdx.x * RPB;

  // ---- stage rows to LDS: coalesced float4 loads (chunk k*256+t, lane-contig),
  //      ds_write_b128 to swizzled chunk sigma(c)=c^((c>>3)&7) (involution).
  //      sigma is a bijection within each 1KB span -> write banks as dense. ----
  float4 st[RPB][4];
#pragma unroll
  for (int r = 0; r < RPB; ++r) {
    const float4* row4 = reinterpret_cast<const float4*>(x + (row0 + r) * NCOL);
#pragma unroll
    for (int k = 0; k < 4; ++k)
      st[r][k] = row4[k * 256 + t];
  }
#pragma unroll
  for (int r = 0; r < RPB; ++r) {
#pragma unroll
    for (int k = 0; k < 4; ++k) {
      const int c = (k * 256 + t) ^ ((t >> 3) & 7);  // 16B-chunk index, swizzled
      *reinterpret_cast<float4*>(&lds[r][c * 4]) = st[r][k];
    }
  }
  __syncthreads();

  // ---- phase-1 fragment read: thread t gets x words [t*16 .. t*16+15] ----
  float v[RPB][16];
#pragma unroll
  for (int r = 0; r < RPB; ++r) {
#pragma unroll
    for (int k = 0; k < 4; ++k) {
      int ba = (t * 64 + k * 16) ^ (((t >> 1) & 7) << 4);  // swizzled byte addr
      float4 q = *reinterpret_cast<const float4*>(
          reinterpret_cast<const char*>(&lds[r][0]) + ba);
      v[r][4 * k + 0] = q.x; v[r][4 * k + 1] = q.y;
      v[r][4 * k + 2] = q.z; v[r][4 * k + 3] = q.w;
    }
  }

  float2 A[8];

  // ---- phase 1: stages 0..3 (bits 0-3 thread-local) ----
#pragma unroll
  for (int s = 0; s < 4; ++s) {
    load_A<TAB>(s, t, tab4, ang, A);
    const int qq = s & 3, d = 1 << qq;
#pragma unroll
    for (int r = 0; r < RPB; ++r) {
#pragma unroll
      for (int p = 0; p < 8; ++p) {
        const int j0 = ((p >> qq) << (qq + 1)) | (p & (d - 1));
        const int j1 = j0 + d;
        float v0 = v[r][j0], v1 = v[r][j1];
        v[r][j0] = A[p].x * v0 - A[p].y * v1;
        v[r][j1] = A[p].y * v0 + A[p].x * v1;
      }
    }
  }
  __syncthreads();

  // ---- exchange 1: write phase-2 layout (elem thi*256 + i*16 + tlo) ----
#pragma unroll
  for (int r = 0; r < RPB; ++r)
#pragma unroll
    for (int j = 0; j < 16; ++j)
      lds[r][swz1(thi * 256 + j * 16 + tlo)] = v[r][j];
  __syncthreads();

#pragma unroll
  for (int r = 0; r < RPB; ++r) {
#pragma unroll
    for (int k = 0; k < 4; ++k) {
      float4 q = *reinterpret_cast<const float4*>(&lds[r][swz1(thi * 256 + tlo * 16 + 4 * k)]);
      v[r][4 * k + 0] = q.x; v[r][4 * k + 1] = q.y;
      v[r][4 * k + 2] = q.z; v[r][4 * k + 3] = q.w;
    }
  }

  // ---- phase 2: stages 4..7 (bits 4-7 thread-local) ----
#pragma unroll
  for (int s = 4; s < 8; ++s) {
    load_A<TAB>(s, t, tab4, ang, A);
    const int qq = s & 3, d = 1 << qq;
#pragma unroll
    for (int r = 0; r < RPB; ++r) {
#pragma unroll
      for (int p = 0; p < 8; ++p) {
        const int j0 = ((p >> qq) << (qq + 1)) | (p & (d - 1));
        const int j1 = j0 + d;
        float v0 = v[r][j0], v1 = v[r][j1];
        v[r][j0] = A[p].x * v0 - A[p].y * v1;
        v[r][j1] = A[p].y * v0 + A[p].x * v1;
      }
    }
  }
  __syncthreads();

  // ---- exchange 2: write phase-3 layout (elem i*256 + t) ----
#pragma unroll
  for (int r = 0; r < RPB; ++r)
#pragma unroll
    for (int j = 0; j < 16; ++j)
      lds[r][swz2(j * 256 + tlo * 16 + thi)] = v[r][j];
  __syncthreads();

#pragma unroll
  for (int r = 0; r < RPB; ++r) {
#pragma unroll
    for (int k = 0; k < 4; ++k) {
      float4 q = *reinterpret_cast<const float4*>(&lds[r][swz2(thi * 256 + tlo * 16 + 4 * k)]);
      v[r][4 * k + 0] = q.x; v[r][4 * k + 1] = q.y;
      v[r][4 * k + 2] = q.z; v[r][4 * k + 3] = q.w;
    }
  }

  // ---- phase 3: stages 8..11 (bits 8-11 thread-local) ----
#pragma unroll
  for (int s = 8; s < 12; ++s) {
    load_A<TAB>(s, t, tab4, ang, A);
    const int qq = s & 3, d = 1 << qq;
#pragma unroll
    for (int r = 0; r < RPB; ++r) {
#pragma unroll
      for (int p = 0; p < 8; ++p) {
        const int j0 = ((p >> qq) << (qq + 1)) | (p & (d - 1));
        const int j1 = j0 + d;
        float v0 = v[r][j0], v1 = v[r][j1];
        v[r][j0] = A[p].x * v0 - A[p].y * v1;
        v[r][j1] = A[p].y * v0 + A[p].x * v1;
      }
    }
  }

  // ---- store (elem i*256 + t: lanes contiguous, coalesced) ----
#pragma unroll
  for (int r = 0; r < RPB; ++r) {
    float* orow = out + (row0 + r) * NCOL;
#pragma unroll
    for (int i = 0; i < 16; ++i)
      orow[i * 256 + t] = v[r][i];
  }
}

extern "C" void kernel_launch(void* const* d_in, const int* in_sizes, int n_in,
                              void* d_out, int out_size, void* d_ws, size_t ws_size,
                              hipStream_t stream) {
  const float* x   = (const float*)d_in[0];
  const float* ang = (const float*)d_in[1];
  float* out       = (float*)d_out;

  const size_t tab_bytes = (size_t)NSTAGES * 4 * 256 * sizeof(float4);  // 192 KB
  const int nblocks = NROWS / RPB;

  if (ws_size >= tab_bytes) {
    float4* tab4 = (float4*)d_ws;
    cs_table_kernel<<<(NSTAGES * 4 * 256 + 255) / 256, 256, 0, stream>>>(ang, tab4);
    butterfly_kernel<true><<<nblocks, 256, 0, stream>>>(x, tab4, nullptr, out);
  } else {
    butterfly_kernel<false><<<nblocks, 256, 0, stream>>>(x, nullptr, ang, out);
  }
}